// Round 1
// baseline (1901.580 us; speedup 1.0000x reference)
//
#include <hip/hip_runtime.h>
#include <hip/hip_bf16.h>
#include <math.h>

// Problem: B=8, T=1024, C=768, H=12, D=64
// x:[1,B,T,C] f32, w_attn:[C,3C], b_attn:[3C], w_proj:[C,C], b_proj:[C]
// out:[1,B,T,C] f32

#define Bq 8
#define Tq 1024
#define Cq 768
#define Hq 12
#define Dq 64
#define MROWS (Bq*Tq)      // 8192
#define N_QKV (3*Cq)       // 2304

// ---------------- QKV GEMM: qkv = x@w_attn + b_attn, scatter to [B,H,T,D] ----
__global__ __launch_bounds__(256) void qkv_gemm(const float* __restrict__ x,
                                                const float* __restrict__ w,
                                                const float* __restrict__ bias,
                                                float* __restrict__ q,
                                                float* __restrict__ k,
                                                float* __restrict__ v) {
    __shared__ float As[16][65];   // [kk][m] transposed
    __shared__ float Bs[16][64];   // [kk][n]
    const int t = threadIdx.x;
    const int bn0 = blockIdx.x * 64;
    const int bm0 = blockIdx.y * 64;
    const int tx = t & 15, ty = t >> 4;
    const int a_i  = t >> 2;        // 0..63
    const int a_k4 = (t & 3) * 4;   // 0,4,8,12
    const int b_k  = t >> 4;        // 0..15
    const int b_j4 = (t & 15) * 4;  // 0..60

    float acc[4][4] = {};
    for (int k0 = 0; k0 < Cq; k0 += 16) {
        float4 av = *reinterpret_cast<const float4*>(x + (size_t)(bm0 + a_i) * Cq + k0 + a_k4);
        As[a_k4 + 0][a_i] = av.x;
        As[a_k4 + 1][a_i] = av.y;
        As[a_k4 + 2][a_i] = av.z;
        As[a_k4 + 3][a_i] = av.w;
        float4 bv = *reinterpret_cast<const float4*>(w + (size_t)(k0 + b_k) * N_QKV + bn0 + b_j4);
        *reinterpret_cast<float4*>(&Bs[b_k][b_j4]) = bv;
        __syncthreads();
        #pragma unroll
        for (int kk = 0; kk < 16; ++kk) {
            float a[4], bb[4];
            #pragma unroll
            for (int r = 0; r < 4; ++r) a[r] = As[kk][ty * 4 + r];
            #pragma unroll
            for (int c = 0; c < 4; ++c) bb[c] = Bs[kk][tx * 4 + c];
            #pragma unroll
            for (int r = 0; r < 4; ++r)
                #pragma unroll
                for (int c = 0; c < 4; ++c) acc[r][c] += a[r] * bb[c];
        }
        __syncthreads();
    }
    // epilogue: bias + scatter to q/k/v in [B,H,T,D]
    #pragma unroll
    for (int r = 0; r < 4; ++r) {
        const int m = bm0 + ty * 4 + r;
        const int bb = m >> 10, tt = m & 1023;
        #pragma unroll
        for (int c = 0; c < 4; ++c) {
            const int n = bn0 + tx * 4 + c;
            const float val = acc[r][c] + bias[n];
            const int which = n / Cq;
            const int hn = n % Cq;
            const int h = hn >> 6, d = hn & 63;
            float* dst = which == 0 ? q : (which == 1 ? k : v);
            dst[(((size_t)bb * Hq + h) * Tq + tt) * Dq + d] = val;
        }
    }
}

// ---------------- Flash causal attention (fp32) ------------------------------
__global__ __launch_bounds__(256) void attn_flash(const float* __restrict__ q,
                                                  const float* __restrict__ k,
                                                  const float* __restrict__ v,
                                                  float* __restrict__ y) {
    __shared__ float Ks[64][65];
    __shared__ float Vs[64][65];
    __shared__ float Ps[64][65];
    const int t = threadIdx.x;
    const int qb = blockIdx.x;          // q tile (0..15)
    const int bh = blockIdx.y;          // b*H+h (0..95)
    const int b = bh / Hq, h = bh % Hq;
    const int row = t >> 2;             // 0..63
    const int part = t & 3;             // 0..3, owns 16 cols
    const size_t head_off = (size_t)bh * Tq * Dq;

    // stage Q tile through LDS (coalesced), then row into registers
    {
        const float* qp = q + head_off + (size_t)qb * 64 * Dq;
        for (int u = 0; u < 16; ++u) {
            int flat = u * 256 + t;
            Ps[flat >> 6][flat & 63] = qp[flat];
        }
    }
    __syncthreads();
    float qreg[64];
    #pragma unroll
    for (int d = 0; d < 64; ++d) qreg[d] = Ps[row][d] * 0.125f;  // fold 1/sqrt(D)
    __syncthreads();

    float O[16] = {};
    float m_run = -INFINITY, l_run = 0.f;
    const int row_g = qb * 64 + row;

    for (int kb = 0; kb <= qb; ++kb) {
        const float* kp = k + head_off + (size_t)kb * 64 * Dq;
        const float* vp = v + head_off + (size_t)kb * 64 * Dq;
        for (int u = 0; u < 16; ++u) {
            int flat = u * 256 + t;
            Ks[flat >> 6][flat & 63] = kp[flat];
            Vs[flat >> 6][flat & 63] = vp[flat];
        }
        __syncthreads();

        float p[16];
        float m_t = -INFINITY;
        #pragma unroll 4
        for (int jj = 0; jj < 16; ++jj) {
            const int j = part * 16 + jj;
            float s = 0.f;
            #pragma unroll
            for (int d = 0; d < 64; ++d) s += qreg[d] * Ks[j][d];
            const bool valid = (kb * 64 + j) <= row_g;
            p[jj] = valid ? s : -INFINITY;
            m_t = fmaxf(m_t, p[jj]);
        }
        m_t = fmaxf(m_t, __shfl_xor(m_t, 1));
        m_t = fmaxf(m_t, __shfl_xor(m_t, 2));
        const float m_new = fmaxf(m_run, m_t);
        const float alpha = expf(m_run - m_new);   // first iter: exp(-inf)=0
        float l_t = 0.f;
        #pragma unroll
        for (int jj = 0; jj < 16; ++jj) {
            p[jj] = expf(p[jj] - m_new);           // masked -> exp(-inf)=0
            l_t += p[jj];
        }
        l_t += __shfl_xor(l_t, 1);
        l_t += __shfl_xor(l_t, 2);
        l_run = l_run * alpha + l_t;
        m_run = m_new;
        #pragma unroll
        for (int dd = 0; dd < 16; ++dd) O[dd] *= alpha;
        #pragma unroll
        for (int jj = 0; jj < 16; ++jj) Ps[row][part * 16 + jj] = p[jj];
        __syncthreads();
        #pragma unroll 4
        for (int j = 0; j < 64; ++j) {
            const float pj = Ps[row][j];
            #pragma unroll
            for (int dd = 0; dd < 16; ++dd) O[dd] += pj * Vs[j][part * 16 + dd];
        }
        __syncthreads();
    }

    const float inv = 1.f / l_run;
    float* yp = y + ((size_t)b * Tq + row_g) * Cq + h * Dq + part * 16;
    #pragma unroll
    for (int dd = 0; dd < 16; ++dd) yp[dd] = O[dd] * inv;
}

// ---------------- Proj GEMM: out = y@w_proj + b_proj -------------------------
__global__ __launch_bounds__(256) void proj_gemm(const float* __restrict__ A,
                                                 const float* __restrict__ w,
                                                 const float* __restrict__ bias,
                                                 float* __restrict__ out) {
    __shared__ float As[16][65];
    __shared__ float Bs[16][64];
    const int t = threadIdx.x;
    const int bn0 = blockIdx.x * 64;
    const int bm0 = blockIdx.y * 64;
    const int tx = t & 15, ty = t >> 4;
    const int a_i  = t >> 2;
    const int a_k4 = (t & 3) * 4;
    const int b_k  = t >> 4;
    const int b_j4 = (t & 15) * 4;

    float acc[4][4] = {};
    for (int k0 = 0; k0 < Cq; k0 += 16) {
        float4 av = *reinterpret_cast<const float4*>(A + (size_t)(bm0 + a_i) * Cq + k0 + a_k4);
        As[a_k4 + 0][a_i] = av.x;
        As[a_k4 + 1][a_i] = av.y;
        As[a_k4 + 2][a_i] = av.z;
        As[a_k4 + 3][a_i] = av.w;
        float4 bv = *reinterpret_cast<const float4*>(w + (size_t)(k0 + b_k) * Cq + bn0 + b_j4);
        *reinterpret_cast<float4*>(&Bs[b_k][b_j4]) = bv;
        __syncthreads();
        #pragma unroll
        for (int kk = 0; kk < 16; ++kk) {
            float a[4], bb[4];
            #pragma unroll
            for (int r = 0; r < 4; ++r) a[r] = As[kk][ty * 4 + r];
            #pragma unroll
            for (int c = 0; c < 4; ++c) bb[c] = Bs[kk][tx * 4 + c];
            #pragma unroll
            for (int r = 0; r < 4; ++r)
                #pragma unroll
                for (int c = 0; c < 4; ++c) acc[r][c] += a[r] * bb[c];
        }
        __syncthreads();
    }
    #pragma unroll
    for (int r = 0; r < 4; ++r) {
        const int m = bm0 + ty * 4 + r;
        #pragma unroll
        for (int c = 0; c < 4; ++c) {
            const int n = bn0 + tx * 4 + c;
            out[(size_t)m * Cq + n] = acc[r][c] + bias[n];
        }
    }
}

extern "C" void kernel_launch(void* const* d_in, const int* in_sizes, int n_in,
                              void* d_out, int out_size, void* d_ws, size_t ws_size,
                              hipStream_t stream) {
    const float* x      = (const float*)d_in[0];
    const float* w_attn = (const float*)d_in[1];
    const float* b_attn = (const float*)d_in[2];
    const float* w_proj = (const float*)d_in[3];
    const float* b_proj = (const float*)d_in[4];
    float* out = (float*)d_out;

    const size_t per = (size_t)Bq * Hq * Tq * Dq;  // 6291456 floats
    float* q = (float*)d_ws;
    float* k = q + per;
    float* v = k + per;
    float* y = v + per;

    qkv_gemm<<<dim3(N_QKV / 64, MROWS / 64), 256, 0, stream>>>(x, w_attn, b_attn, q, k, v);
    attn_flash<<<dim3(Tq / 64, Bq * Hq), 256, 0, stream>>>(q, k, v, y);
    proj_gemm<<<dim3(Cq / 64, MROWS / 64), 256, 0, stream>>>(y, w_proj, b_proj, out);
}

// Round 2
// 214.466 us; speedup vs baseline: 8.8666x; 8.8666x over previous
//
#include <hip/hip_runtime.h>
#include <hip/hip_bf16.h>
#include <math.h>

// B=8, T=1024, C=768, H=12, D=64
#define Bq 8
#define Tq 1024
#define Cq 768
#define Hq 12
#define Dq 64
#define MROWS (Bq*Tq)      // 8192
#define N_QKV (3*Cq)       // 2304

typedef __bf16 bf16;
typedef bf16 bf16x8 __attribute__((ext_vector_type(8)));
typedef float f32x4 __attribute__((ext_vector_type(4)));

#define MFMA16x16x32(a, b, c) __builtin_amdgcn_mfma_f32_16x16x32_bf16((a), (b), (c), 0, 0, 0)

// All LDS tiles have 128-byte rows (64 bf16). XOR-swizzle 16B chunks within a
// row by the row's low 3 bits (T2) -> stride-128B column reads become ~conflict-free.
__device__ __forceinline__ bf16x8& lds_v8(bf16* base, int row, int byteoff) {
    return *reinterpret_cast<bf16x8*>(
        reinterpret_cast<char*>(base) + row * 128 + (byteoff ^ ((row & 7) << 4)));
}
__device__ __forceinline__ bf16& lds_s16(bf16* base, int row, int byteoff) {
    return *reinterpret_cast<bf16*>(
        reinterpret_cast<char*>(base) + row * 128 + (byteoff ^ ((row & 7) << 4)));
}

// ---------------- helpers: f32 -> bf16 convert / transpose -------------------
__global__ __launch_bounds__(256) void f32_to_bf16(const float* __restrict__ in,
                                                   bf16* __restrict__ out, int n8) {
    int i = blockIdx.x * 256 + threadIdx.x;
    if (i >= n8) return;
    const float4* p = reinterpret_cast<const float4*>(in) + (size_t)i * 2;
    float4 a = p[0], b = p[1];
    bf16x8 o;
    o[0] = (bf16)a.x; o[1] = (bf16)a.y; o[2] = (bf16)a.z; o[3] = (bf16)a.w;
    o[4] = (bf16)b.x; o[5] = (bf16)b.y; o[6] = (bf16)b.z; o[7] = (bf16)b.w;
    reinterpret_cast<bf16x8*>(out)[i] = o;
}

// in[R][C] (f32) -> out[C][R] (bf16)
__global__ __launch_bounds__(256) void transpose_f32_bf16(const float* __restrict__ in,
                                                          bf16* __restrict__ out,
                                                          int R, int C) {
    int idx = blockIdx.x * 256 + threadIdx.x;
    if (idx >= R * C) return;
    int c = idx / R;      // output row
    int r = idx - c * R;  // output col
    out[idx] = (bf16)in[(size_t)r * C + c];
}

// ---------------- QKV GEMM (bf16 MFMA): [8192x768]x[768x2304] ----------------
// A: x bf16 [M][K] row-major; Bt: w_attn^T bf16 [N][K] row-major.
// Epilogue scatters: Q(x0.125),K -> [B,H,T,D]; V -> transposed [B,H,D,T].
__global__ __launch_bounds__(256) void gemm_qkv(const bf16* __restrict__ A,
                                                const bf16* __restrict__ Bt,
                                                const float* __restrict__ bias,
                                                bf16* __restrict__ Qo,
                                                bf16* __restrict__ Ko,
                                                bf16* __restrict__ Vto) {
    __shared__ bf16 As[128 * 64];
    __shared__ bf16 Bs[128 * 64];
    const int tid = threadIdx.x;
    const int w = tid >> 6, l = tid & 63;
    const int lane16 = l & 15, kg = l >> 4;
    const int wr = w >> 1, wc = w & 1;
    const int bn0 = blockIdx.x * 128, bm0 = blockIdx.y * 128;

    f32x4 acc[4][4] = {};
    for (int k0 = 0; k0 < Cq; k0 += 64) {
        #pragma unroll
        for (int it = 0; it < 4; ++it) {
            const int c = it * 256 + tid;        // 0..1023 chunk (16B) index
            const int r = c >> 3, c16 = c & 7;   // 128 rows x 8 chunks
            lds_v8(As, r, c16 * 16) =
                *reinterpret_cast<const bf16x8*>(A + (size_t)(bm0 + r) * Cq + k0 + c16 * 8);
            lds_v8(Bs, r, c16 * 16) =
                *reinterpret_cast<const bf16x8*>(Bt + (size_t)(bn0 + r) * Cq + k0 + c16 * 8);
        }
        __syncthreads();
        #pragma unroll
        for (int ks = 0; ks < 2; ++ks) {
            bf16x8 af[4], bfr[4];
            #pragma unroll
            for (int m = 0; m < 4; ++m)
                af[m] = lds_v8(As, wr * 64 + m * 16 + lane16, ks * 64 + kg * 16);
            #pragma unroll
            for (int n = 0; n < 4; ++n)
                bfr[n] = lds_v8(Bs, wc * 64 + n * 16 + lane16, ks * 64 + kg * 16);
            #pragma unroll
            for (int m = 0; m < 4; ++m)
                #pragma unroll
                for (int n = 0; n < 4; ++n)
                    acc[m][n] = MFMA16x16x32(af[m], bfr[n], acc[m][n]);
        }
        __syncthreads();
    }
    const int mrow0 = bm0 + wr * 64;
    const int ncol0 = bn0 + wc * 64;
    #pragma unroll
    for (int mi = 0; mi < 4; ++mi) {
        #pragma unroll
        for (int r = 0; r < 4; ++r) {
            const int grow = mrow0 + mi * 16 + kg * 4 + r;
            const int bb = grow >> 10, tt = grow & 1023;
            #pragma unroll
            for (int ni = 0; ni < 4; ++ni) {
                const int gcol = ncol0 + ni * 16 + lane16;
                const float v = acc[mi][ni][r] + bias[gcol];
                const int which = gcol / Cq;
                const int hn = gcol - which * Cq;
                const int h = hn >> 6, d = hn & 63;
                const size_t bh = (size_t)bb * Hq + h;
                if (which == 0)      Qo[(bh * Tq + tt) * Dq + d] = (bf16)(v * 0.125f);
                else if (which == 1) Ko[(bh * Tq + tt) * Dq + d] = (bf16)v;
                else                 Vto[(bh * Dq + d) * Tq + tt] = (bf16)v;
            }
        }
    }
}

// ---------------- Flash causal attention (bf16 MFMA) -------------------------
// Block: 256 thr / 4 waves; block owns 64 q-rows (wave w: rows qb*64+w*16..+16).
// KV tiles of 64. K in LDS [kcol][d], V in LDS [d][kcol] (from Vt ws), both
// swizzled. Online softmax per C-frag row; P staged bf16 through LDS.
__global__ __launch_bounds__(256) void attn_mfma(const bf16* __restrict__ Q,
                                                 const bf16* __restrict__ K,
                                                 const bf16* __restrict__ Vt,
                                                 bf16* __restrict__ Y) {
    __shared__ bf16 Kl[64 * 64];
    __shared__ bf16 Vl[64 * 64];
    __shared__ bf16 Pl[4 * 16 * 64];
    const int tid = threadIdx.x;
    const int w = tid >> 6, l = tid & 63;
    const int lane16 = l & 15, kg = l >> 4;
    const int qb = blockIdx.x, bh = blockIdx.y;
    const size_t hoff = (size_t)bh * Tq * Dq;
    bf16* Pw = Pl + w * 16 * 64;

    const int qrow = qb * 64 + w * 16;
    const bf16x8 qf0 = *reinterpret_cast<const bf16x8*>(Q + hoff + (size_t)(qrow + lane16) * Dq + kg * 8);
    const bf16x8 qf1 = *reinterpret_cast<const bf16x8*>(Q + hoff + (size_t)(qrow + lane16) * Dq + 32 + kg * 8);

    f32x4 of[4] = {};
    float mrun[4], lrun[4];
    #pragma unroll
    for (int r = 0; r < 4; ++r) { mrun[r] = -INFINITY; lrun[r] = 0.f; }
    const int qg0 = qrow + kg * 4;

    for (int kb = 0; kb <= qb; ++kb) {
        #pragma unroll
        for (int it = 0; it < 2; ++it) {
            const int c = it * 256 + tid;       // 0..511
            const int r = c >> 3, c16 = c & 7;  // 64 rows x 8 chunks
            lds_v8(Kl, r, c16 * 16) =
                *reinterpret_cast<const bf16x8*>(K + hoff + (size_t)(kb * 64 + r) * Dq + c16 * 8);
            lds_v8(Vl, r, c16 * 16) =
                *reinterpret_cast<const bf16x8*>(Vt + hoff + (size_t)r * Tq + kb * 64 + c16 * 8);
        }
        __syncthreads();

        // S = Q K^T  (16 q-rows x 64 kcols per wave)
        f32x4 sf[4];
        #pragma unroll
        for (int f = 0; f < 4; ++f) {
            f32x4 z = {};
            bf16x8 b0 = lds_v8(Kl, f * 16 + lane16, kg * 16);
            bf16x8 b1 = lds_v8(Kl, f * 16 + lane16, 64 + kg * 16);
            z = MFMA16x16x32(qf0, b0, z);
            z = MFMA16x16x32(qf1, b1, z);
            sf[f] = z;
        }
        if (kb == qb) {  // causal mask only on the diagonal tile
            #pragma unroll
            for (int f = 0; f < 4; ++f)
                #pragma unroll
                for (int r = 0; r < 4; ++r)
                    if (kb * 64 + f * 16 + lane16 > qg0 + r) sf[f][r] = -INFINITY;
        }
        float mt[4];
        #pragma unroll
        for (int r = 0; r < 4; ++r) mt[r] = -INFINITY;
        #pragma unroll
        for (int f = 0; f < 4; ++f)
            #pragma unroll
            for (int r = 0; r < 4; ++r) mt[r] = fmaxf(mt[r], sf[f][r]);
        #pragma unroll
        for (int r = 0; r < 4; ++r) {
            #pragma unroll
            for (int m = 1; m < 16; m <<= 1) mt[r] = fmaxf(mt[r], __shfl_xor(mt[r], m));
            const float mn = fmaxf(mrun[r], mt[r]);
            const float a = __expf(mrun[r] - mn);
            mrun[r] = mn;
            lrun[r] *= a;
            #pragma unroll
            for (int dg = 0; dg < 4; ++dg) of[dg][r] *= a;
        }
        float lt[4] = {0.f, 0.f, 0.f, 0.f};
        #pragma unroll
        for (int f = 0; f < 4; ++f)
            #pragma unroll
            for (int r = 0; r < 4; ++r) {
                const float p = __expf(sf[f][r] - mrun[r]);
                lt[r] += p;
                lds_s16(Pw, kg * 4 + r, (f * 16 + lane16) * 2) = (bf16)p;
            }
        #pragma unroll
        for (int r = 0; r < 4; ++r) {
            #pragma unroll
            for (int m = 1; m < 16; m <<= 1) lt[r] += __shfl_xor(lt[r], m);
            lrun[r] += lt[r];
        }
        // O += P V   (P: wave-local LDS; V: Vl rows are d)
        #pragma unroll
        for (int ks = 0; ks < 2; ++ks) {
            bf16x8 pf = lds_v8(Pw, lane16, ks * 64 + kg * 16);
            #pragma unroll
            for (int dg = 0; dg < 4; ++dg) {
                bf16x8 vf = lds_v8(Vl, dg * 16 + lane16, ks * 64 + kg * 16);
                of[dg] = MFMA16x16x32(pf, vf, of[dg]);
            }
        }
        __syncthreads();
    }

    const int b = bh / Hq, h = bh - b * Hq;
    #pragma unroll
    for (int r = 0; r < 4; ++r) {
        const float inv = 1.f / lrun[r];
        const int q = qg0 + r;
        bf16* yp = Y + (size_t)(b * Tq + q) * Cq + h * Dq;
        #pragma unroll
        for (int dg = 0; dg < 4; ++dg)
            yp[dg * 16 + lane16] = (bf16)(of[dg][r] * inv);
    }
}

// ---------------- Proj GEMM (bf16 MFMA): [8192x768]x[768x768] + bias -> f32 --
__global__ __launch_bounds__(256) void gemm_proj(const bf16* __restrict__ A,
                                                 const bf16* __restrict__ Bt,
                                                 const float* __restrict__ bias,
                                                 float* __restrict__ out) {
    __shared__ bf16 As[128 * 64];
    __shared__ bf16 Bs[128 * 64];
    const int tid = threadIdx.x;
    const int w = tid >> 6, l = tid & 63;
    const int lane16 = l & 15, kg = l >> 4;
    const int wr = w >> 1, wc = w & 1;
    const int bn0 = blockIdx.x * 128, bm0 = blockIdx.y * 128;

    f32x4 acc[4][4] = {};
    for (int k0 = 0; k0 < Cq; k0 += 64) {
        #pragma unroll
        for (int it = 0; it < 4; ++it) {
            const int c = it * 256 + tid;
            const int r = c >> 3, c16 = c & 7;
            lds_v8(As, r, c16 * 16) =
                *reinterpret_cast<const bf16x8*>(A + (size_t)(bm0 + r) * Cq + k0 + c16 * 8);
            lds_v8(Bs, r, c16 * 16) =
                *reinterpret_cast<const bf16x8*>(Bt + (size_t)(bn0 + r) * Cq + k0 + c16 * 8);
        }
        __syncthreads();
        #pragma unroll
        for (int ks = 0; ks < 2; ++ks) {
            bf16x8 af[4], bfr[4];
            #pragma unroll
            for (int m = 0; m < 4; ++m)
                af[m] = lds_v8(As, wr * 64 + m * 16 + lane16, ks * 64 + kg * 16);
            #pragma unroll
            for (int n = 0; n < 4; ++n)
                bfr[n] = lds_v8(Bs, wc * 64 + n * 16 + lane16, ks * 64 + kg * 16);
            #pragma unroll
            for (int m = 0; m < 4; ++m)
                #pragma unroll
                for (int n = 0; n < 4; ++n)
                    acc[m][n] = MFMA16x16x32(af[m], bfr[n], acc[m][n]);
        }
        __syncthreads();
    }
    const int mrow0 = bm0 + wr * 64;
    const int ncol0 = bn0 + wc * 64;
    #pragma unroll
    for (int mi = 0; mi < 4; ++mi) {
        #pragma unroll
        for (int r = 0; r < 4; ++r) {
            const int grow = mrow0 + mi * 16 + kg * 4 + r;
            #pragma unroll
            for (int ni = 0; ni < 4; ++ni) {
                const int gcol = ncol0 + ni * 16 + lane16;
                out[(size_t)grow * Cq + gcol] = acc[mi][ni][r] + bias[gcol];
            }
        }
    }
}

extern "C" void kernel_launch(void* const* d_in, const int* in_sizes, int n_in,
                              void* d_out, int out_size, void* d_ws, size_t ws_size,
                              hipStream_t stream) {
    const float* x      = (const float*)d_in[0];
    const float* w_attn = (const float*)d_in[1];
    const float* b_attn = (const float*)d_in[2];
    const float* w_proj = (const float*)d_in[3];
    const float* b_proj = (const float*)d_in[4];
    float* out = (float*)d_out;

    char* ws = (char*)d_ws;
    bf16* Ax  = (bf16*)ws; ws += (size_t)MROWS * Cq * 2;   // x in bf16
    bf16* WaT = (bf16*)ws; ws += (size_t)N_QKV * Cq * 2;   // w_attn^T
    bf16* WpT = (bf16*)ws; ws += (size_t)Cq * Cq * 2;      // w_proj^T
    bf16* Qw  = (bf16*)ws; ws += (size_t)MROWS * Cq * 2;   // [B,H,T,D], x0.125
    bf16* Kw  = (bf16*)ws; ws += (size_t)MROWS * Cq * 2;   // [B,H,T,D]
    bf16* Vtw = (bf16*)ws; ws += (size_t)MROWS * Cq * 2;   // [B,H,D,T]
    bf16* Yw  = (bf16*)ws; ws += (size_t)MROWS * Cq * 2;   // attn out [M][C]

    f32_to_bf16<<<(MROWS * Cq / 8 + 255) / 256, 256, 0, stream>>>(x, Ax, MROWS * Cq / 8);
    transpose_f32_bf16<<<(Cq * N_QKV + 255) / 256, 256, 0, stream>>>(w_attn, WaT, Cq, N_QKV);
    transpose_f32_bf16<<<(Cq * Cq + 255) / 256, 256, 0, stream>>>(w_proj, WpT, Cq, Cq);
    gemm_qkv<<<dim3(N_QKV / 128, MROWS / 128), 256, 0, stream>>>(Ax, WaT, b_attn, Qw, Kw, Vtw);
    attn_mfma<<<dim3(Tq / 64, Bq * Hq), 256, 0, stream>>>(Qw, Kw, Vtw, Yw);
    gemm_proj<<<dim3(Cq / 128, MROWS / 128), 256, 0, stream>>>(Yw, WpT, b_proj, out);
}

// Round 3
// 173.439 us; speedup vs baseline: 10.9640x; 1.2366x over previous
//
#include <hip/hip_runtime.h>
#include <hip/hip_bf16.h>
#include <math.h>

// B=8, T=1024, C=768, H=12, D=64
#define Bq 8
#define Tq 1024
#define Cq 768
#define Hq 12
#define Dq 64
#define MROWS (Bq*Tq)      // 8192
#define N_QKV (3*Cq)       // 2304

typedef __bf16 bf16;
typedef bf16 bf16x8 __attribute__((ext_vector_type(8)));
typedef float f32x4 __attribute__((ext_vector_type(4)));

#define MFMA16x16x32(a, b, c) __builtin_amdgcn_mfma_f32_16x16x32_bf16((a), (b), (c), 0, 0, 0)

// All LDS tiles have 128-byte rows (64 bf16). XOR-swizzle 16B chunks within a
// row by the row's low 3 bits (T2) -> stride-128B column reads conflict-free.
__device__ __forceinline__ bf16x8& lds_v8(bf16* base, int row, int byteoff) {
    return *reinterpret_cast<bf16x8*>(
        reinterpret_cast<char*>(base) + row * 128 + (byteoff ^ ((row & 7) << 4)));
}
__device__ __forceinline__ bf16& lds_s16(bf16* base, int row, int byteoff) {
    return *reinterpret_cast<bf16*>(
        reinterpret_cast<char*>(base) + row * 128 + (byteoff ^ ((row & 7) << 4)));
}

// async global->LDS DMA, 16B per lane; LDS dest is wave-uniform base + lane*16.
// Content swizzle is achieved by pre-swizzling the per-lane GLOBAL source.
typedef __attribute__((address_space(3))) unsigned int lds_u32;
typedef const __attribute__((address_space(1))) unsigned int glb_u32;
__device__ __forceinline__ void gload16(const void* g, void* lds) {
    __builtin_amdgcn_global_load_lds((glb_u32*)(uintptr_t)g,
                                     (lds_u32*)(unsigned int)(uintptr_t)lds,
                                     16, 0, 0);
}

// ---------------- helpers: f32 -> bf16 convert / transpose -------------------
__global__ __launch_bounds__(256) void f32_to_bf16(const float* __restrict__ in,
                                                   bf16* __restrict__ out, int n8) {
    int i = blockIdx.x * 256 + threadIdx.x;
    if (i >= n8) return;
    const float4* p = reinterpret_cast<const float4*>(in) + (size_t)i * 2;
    float4 a = p[0], b = p[1];
    bf16x8 o;
    o[0] = (bf16)a.x; o[1] = (bf16)a.y; o[2] = (bf16)a.z; o[3] = (bf16)a.w;
    o[4] = (bf16)b.x; o[5] = (bf16)b.y; o[6] = (bf16)b.z; o[7] = (bf16)b.w;
    reinterpret_cast<bf16x8*>(out)[i] = o;
}

// in[R][C] (f32) -> out[C][R] (bf16)
__global__ __launch_bounds__(256) void transpose_f32_bf16(const float* __restrict__ in,
                                                          bf16* __restrict__ out,
                                                          int R, int C) {
    int idx = blockIdx.x * 256 + threadIdx.x;
    if (idx >= R * C) return;
    int c = idx / R;
    int r = idx - c * R;
    out[idx] = (bf16)in[(size_t)r * C + c];
}

// ---------------- QKV GEMM (bf16 MFMA): [8192x768]x[768x2304] ----------------
__global__ __launch_bounds__(256) void gemm_qkv(const bf16* __restrict__ A,
                                                const bf16* __restrict__ Bt,
                                                const float* __restrict__ bias,
                                                bf16* __restrict__ Qo,
                                                bf16* __restrict__ Ko,
                                                bf16* __restrict__ Vto) {
    __shared__ bf16 As[128 * 64];
    __shared__ bf16 Bs[128 * 64];
    const int tid = threadIdx.x;
    const int w = tid >> 6, l = tid & 63;
    const int lane16 = l & 15, kg = l >> 4;
    const int wr = w >> 1, wc = w & 1;
    const int bn0 = blockIdx.x * 128, bm0 = blockIdx.y * 128;

    f32x4 acc[4][4] = {};
    for (int k0 = 0; k0 < Cq; k0 += 64) {
        #pragma unroll
        for (int j = 0; j < 4; ++j) {
            const int q8 = w * 4 + j;          // 1KB block 0..15
            const int r  = q8 * 8 + (l >> 3);  // tile row 0..127
            const int c16 = (l & 7) ^ (r & 7); // pre-swizzled source chunk
            gload16(A + (size_t)(bm0 + r) * Cq + k0 + c16 * 8, As + q8 * 512);
            gload16(Bt + (size_t)(bn0 + r) * Cq + k0 + c16 * 8, Bs + q8 * 512);
        }
        __syncthreads();
        #pragma unroll
        for (int ks = 0; ks < 2; ++ks) {
            bf16x8 af[4], bfr[4];
            #pragma unroll
            for (int m = 0; m < 4; ++m)
                af[m] = lds_v8(As, wr * 64 + m * 16 + lane16, ks * 64 + kg * 16);
            #pragma unroll
            for (int n = 0; n < 4; ++n)
                bfr[n] = lds_v8(Bs, wc * 64 + n * 16 + lane16, ks * 64 + kg * 16);
            #pragma unroll
            for (int m = 0; m < 4; ++m)
                #pragma unroll
                for (int n = 0; n < 4; ++n)
                    acc[m][n] = MFMA16x16x32(af[m], bfr[n], acc[m][n]);
        }
        __syncthreads();
    }
    const int mrow0 = bm0 + wr * 64;
    const int ncol0 = bn0 + wc * 64;
    #pragma unroll
    for (int mi = 0; mi < 4; ++mi) {
        #pragma unroll
        for (int r = 0; r < 4; ++r) {
            const int grow = mrow0 + mi * 16 + kg * 4 + r;
            const int bb = grow >> 10, tt = grow & 1023;
            #pragma unroll
            for (int ni = 0; ni < 4; ++ni) {
                const int gcol = ncol0 + ni * 16 + lane16;
                const float v = acc[mi][ni][r] + bias[gcol];
                const int which = gcol / Cq;
                const int hn = gcol - which * Cq;
                const int h = hn >> 6, d = hn & 63;
                const size_t bh = (size_t)bb * Hq + h;
                if (which == 0)      Qo[(bh * Tq + tt) * Dq + d] = (bf16)(v * 0.125f);
                else if (which == 1) Ko[(bh * Tq + tt) * Dq + d] = (bf16)v;
                else                 Vto[(bh * Dq + d) * Tq + tt] = (bf16)v;
            }
        }
    }
}

// ---------------- Flash causal attention (bf16 MFMA, paired q-tiles) ---------
// Grid (8, 96): block handles q-tiles {qpair, 15-qpair} -> uniform 17 KV tiles.
// K/V double-buffered in LDS via global_load_lds DMA (pre-swizzled source),
// one barrier per KV tile. 4 waves x 16 q-rows per q-tile.
__global__ __launch_bounds__(256) void attn_mfma(const bf16* __restrict__ Q,
                                                 const bf16* __restrict__ K,
                                                 const bf16* __restrict__ Vt,
                                                 bf16* __restrict__ Y) {
    __shared__ bf16 Kl[2][64 * 64];
    __shared__ bf16 Vl[2][64 * 64];
    __shared__ bf16 Pl[4 * 16 * 64];
    const int tid = threadIdx.x;
    const int w = tid >> 6, l = tid & 63;
    const int lane16 = l & 15, kg = l >> 4;
    const int qlo = blockIdx.x, qhi = 15 - qlo;
    const int bh = blockIdx.y;
    const size_t hoff = (size_t)bh * Tq * Dq;
    bf16* Pw = Pl + w * 16 * 64;
    const int qloc = w * 16 + kg * 4;       // local q-row of frag r=0 within tile

    const int qrow_lo = qlo * 64 + w * 16;
    const int qrow_hi = qhi * 64 + w * 16;
    const bf16x8 qlo0 = *reinterpret_cast<const bf16x8*>(Q + hoff + (size_t)(qrow_lo + lane16) * Dq + kg * 8);
    const bf16x8 qlo1 = *reinterpret_cast<const bf16x8*>(Q + hoff + (size_t)(qrow_lo + lane16) * Dq + 32 + kg * 8);
    const bf16x8 qhi0 = *reinterpret_cast<const bf16x8*>(Q + hoff + (size_t)(qrow_hi + lane16) * Dq + kg * 8);
    const bf16x8 qhi1 = *reinterpret_cast<const bf16x8*>(Q + hoff + (size_t)(qrow_hi + lane16) * Dq + 32 + kg * 8);

    f32x4 o_lo[4] = {}, o_hi[4] = {};
    float m_lo[4], l_lo[4], m_hi[4], l_hi[4];
    #pragma unroll
    for (int r = 0; r < 4; ++r) {
        m_lo[r] = -INFINITY; l_lo[r] = 0.f;
        m_hi[r] = -INFINITY; l_hi[r] = 0.f;
    }

    auto stage = [&](int t, int buf) {
        #pragma unroll
        for (int j = 0; j < 2; ++j) {
            const int q8 = w * 2 + j;          // 0..7 (1KB block)
            const int r  = q8 * 8 + (l >> 3);  // tile row 0..63
            const int c16 = (l & 7) ^ (r & 7);
            gload16(K + hoff + (size_t)(t * 64 + r) * Dq + c16 * 8, &Kl[buf][q8 * 512]);
            gload16(Vt + hoff + (size_t)r * Tq + t * 64 + c16 * 8, &Vl[buf][q8 * 512]);
        }
    };

    auto process = [&](const bf16x8& qf0, const bf16x8& qf1, f32x4* of, float* mr, float* lr,
                       bool diag, bf16* Kc, bf16* Vc) {
        f32x4 sf[4];
        #pragma unroll
        for (int f = 0; f < 4; ++f) {
            f32x4 z = {};
            z = MFMA16x16x32(qf0, lds_v8(Kc, f * 16 + lane16, kg * 16), z);
            z = MFMA16x16x32(qf1, lds_v8(Kc, f * 16 + lane16, 64 + kg * 16), z);
            sf[f] = z;
        }
        if (diag) {
            #pragma unroll
            for (int f = 0; f < 4; ++f)
                #pragma unroll
                for (int r = 0; r < 4; ++r)
                    if (f * 16 + lane16 > qloc + r) sf[f][r] = -INFINITY;
        }
        float mt[4];
        #pragma unroll
        for (int r = 0; r < 4; ++r) mt[r] = -INFINITY;
        #pragma unroll
        for (int f = 0; f < 4; ++f)
            #pragma unroll
            for (int r = 0; r < 4; ++r) mt[r] = fmaxf(mt[r], sf[f][r]);
        #pragma unroll
        for (int r = 0; r < 4; ++r) {
            #pragma unroll
            for (int m = 1; m < 16; m <<= 1) mt[r] = fmaxf(mt[r], __shfl_xor(mt[r], m));
            const float mn = fmaxf(mr[r], mt[r]);
            const float a = __expf(mr[r] - mn);
            mr[r] = mn;
            lr[r] *= a;
            #pragma unroll
            for (int dg = 0; dg < 4; ++dg) of[dg][r] *= a;
        }
        float lt[4] = {0.f, 0.f, 0.f, 0.f};
        #pragma unroll
        for (int f = 0; f < 4; ++f)
            #pragma unroll
            for (int r = 0; r < 4; ++r) {
                const float p = __expf(sf[f][r] - mr[r]);
                lt[r] += p;
                lds_s16(Pw, kg * 4 + r, (f * 16 + lane16) * 2) = (bf16)p;
            }
        #pragma unroll
        for (int r = 0; r < 4; ++r) {
            #pragma unroll
            for (int m = 1; m < 16; m <<= 1) lt[r] += __shfl_xor(lt[r], m);
            lr[r] += lt[r];
        }
        #pragma unroll
        for (int ks = 0; ks < 2; ++ks) {
            bf16x8 pf = lds_v8(Pw, lane16, ks * 64 + kg * 16);
            #pragma unroll
            for (int dg = 0; dg < 4; ++dg) {
                bf16x8 vf = lds_v8(Vc, dg * 16 + lane16, ks * 64 + kg * 16);
                of[dg] = MFMA16x16x32(pf, vf, of[dg]);
            }
        }
    };

    stage(0, 0);
    __syncthreads();

    for (int t = 0; t <= qhi; ++t) {
        if (t < qhi) stage(t + 1, (t + 1) & 1);     // DMA overlaps compute
        bf16* Kc = Kl[t & 1];
        bf16* Vc = Vl[t & 1];
        process(qhi0, qhi1, o_hi, m_hi, l_hi, t == qhi, Kc, Vc);
        if (t <= qlo) process(qlo0, qlo1, o_lo, m_lo, l_lo, t == qlo, Kc, Vc);
        __syncthreads();                            // vmcnt drain = DMA complete
    }

    const int b = bh / Hq, h = bh - b * Hq;
    #pragma unroll
    for (int r = 0; r < 4; ++r) {
        const float ih = 1.f / l_hi[r];
        const float il = 1.f / l_lo[r];
        bf16* yh = Y + (size_t)(b * Tq + qrow_hi + kg * 4 + r) * Cq + h * Dq;
        bf16* yl = Y + (size_t)(b * Tq + qrow_lo + kg * 4 + r) * Cq + h * Dq;
        #pragma unroll
        for (int dg = 0; dg < 4; ++dg) {
            yh[dg * 16 + lane16] = (bf16)(o_hi[dg][r] * ih);
            yl[dg * 16 + lane16] = (bf16)(o_lo[dg][r] * il);
        }
    }
}

// ---------------- Proj GEMM (bf16 MFMA): [8192x768]x[768x768] + bias -> f32 --
__global__ __launch_bounds__(256) void gemm_proj(const bf16* __restrict__ A,
                                                 const bf16* __restrict__ Bt,
                                                 const float* __restrict__ bias,
                                                 float* __restrict__ out) {
    __shared__ bf16 As[128 * 64];
    __shared__ bf16 Bs[128 * 64];
    const int tid = threadIdx.x;
    const int w = tid >> 6, l = tid & 63;
    const int lane16 = l & 15, kg = l >> 4;
    const int wr = w >> 1, wc = w & 1;
    const int bn0 = blockIdx.x * 128, bm0 = blockIdx.y * 128;

    f32x4 acc[4][4] = {};
    for (int k0 = 0; k0 < Cq; k0 += 64) {
        #pragma unroll
        for (int j = 0; j < 4; ++j) {
            const int q8 = w * 4 + j;
            const int r  = q8 * 8 + (l >> 3);
            const int c16 = (l & 7) ^ (r & 7);
            gload16(A + (size_t)(bm0 + r) * Cq + k0 + c16 * 8, As + q8 * 512);
            gload16(Bt + (size_t)(bn0 + r) * Cq + k0 + c16 * 8, Bs + q8 * 512);
        }
        __syncthreads();
        #pragma unroll
        for (int ks = 0; ks < 2; ++ks) {
            bf16x8 af[4], bfr[4];
            #pragma unroll
            for (int m = 0; m < 4; ++m)
                af[m] = lds_v8(As, wr * 64 + m * 16 + lane16, ks * 64 + kg * 16);
            #pragma unroll
            for (int n = 0; n < 4; ++n)
                bfr[n] = lds_v8(Bs, wc * 64 + n * 16 + lane16, ks * 64 + kg * 16);
            #pragma unroll
            for (int m = 0; m < 4; ++m)
                #pragma unroll
                for (int n = 0; n < 4; ++n)
                    acc[m][n] = MFMA16x16x32(af[m], bfr[n], acc[m][n]);
        }
        __syncthreads();
    }
    const int mrow0 = bm0 + wr * 64;
    const int ncol0 = bn0 + wc * 64;
    #pragma unroll
    for (int mi = 0; mi < 4; ++mi) {
        #pragma unroll
        for (int r = 0; r < 4; ++r) {
            const int grow = mrow0 + mi * 16 + kg * 4 + r;
            #pragma unroll
            for (int ni = 0; ni < 4; ++ni) {
                const int gcol = ncol0 + ni * 16 + lane16;
                out[(size_t)grow * Cq + gcol] = acc[mi][ni][r] + bias[gcol];
            }
        }
    }
}

extern "C" void kernel_launch(void* const* d_in, const int* in_sizes, int n_in,
                              void* d_out, int out_size, void* d_ws, size_t ws_size,
                              hipStream_t stream) {
    const float* x      = (const float*)d_in[0];
    const float* w_attn = (const float*)d_in[1];
    const float* b_attn = (const float*)d_in[2];
    const float* w_proj = (const float*)d_in[3];
    const float* b_proj = (const float*)d_in[4];
    float* out = (float*)d_out;

    char* ws = (char*)d_ws;
    bf16* Ax  = (bf16*)ws; ws += (size_t)MROWS * Cq * 2;
    bf16* WaT = (bf16*)ws; ws += (size_t)N_QKV * Cq * 2;
    bf16* WpT = (bf16*)ws; ws += (size_t)Cq * Cq * 2;
    bf16* Qw  = (bf16*)ws; ws += (size_t)MROWS * Cq * 2;   // [B,H,T,D], x0.125
    bf16* Kw  = (bf16*)ws; ws += (size_t)MROWS * Cq * 2;   // [B,H,T,D]
    bf16* Vtw = (bf16*)ws; ws += (size_t)MROWS * Cq * 2;   // [B,H,D,T]
    bf16* Yw  = (bf16*)ws; ws += (size_t)MROWS * Cq * 2;   // attn out [M][C]

    f32_to_bf16<<<(MROWS * Cq / 8 + 255) / 256, 256, 0, stream>>>(x, Ax, MROWS * Cq / 8);
    transpose_f32_bf16<<<(Cq * N_QKV + 255) / 256, 256, 0, stream>>>(w_attn, WaT, Cq, N_QKV);
    transpose_f32_bf16<<<(Cq * Cq + 255) / 256, 256, 0, stream>>>(w_proj, WpT, Cq, Cq);
    gemm_qkv<<<dim3(N_QKV / 128, MROWS / 128), 256, 0, stream>>>(Ax, WaT, b_attn, Qw, Kw, Vtw);
    attn_mfma<<<dim3(8, Bq * Hq), 256, 0, stream>>>(Qw, Kw, Vtw, Yw);
    gemm_proj<<<dim3(Cq / 128, MROWS / 128), 256, 0, stream>>>(Yw, WpT, b_proj, out);
}

// Round 4
// 155.743 us; speedup vs baseline: 12.2098x; 1.1136x over previous
//
#include <hip/hip_runtime.h>
#include <hip/hip_bf16.h>
#include <math.h>

// B=8, T=1024, C=768, H=12, D=64
#define Bq 8
#define Tq 1024
#define Cq 768
#define Hq 12
#define Dq 64
#define MROWS (Bq*Tq)      // 8192
#define N_QKV (3*Cq)       // 2304

typedef __bf16 bf16;
typedef bf16 bf16x8 __attribute__((ext_vector_type(8)));
typedef float f32x4 __attribute__((ext_vector_type(4)));

#define MFMA16x16x32(a, b, c) __builtin_amdgcn_mfma_f32_16x16x32_bf16((a), (b), (c), 0, 0, 0)

// All LDS tiles have 128-byte rows (64 bf16). XOR-swizzle 16B chunks within a
// row by the row's low 3 bits (T2) -> stride-128B column reads conflict-free.
__device__ __forceinline__ bf16x8& lds_v8(bf16* base, int row, int byteoff) {
    return *reinterpret_cast<bf16x8*>(
        reinterpret_cast<char*>(base) + row * 128 + (byteoff ^ ((row & 7) << 4)));
}
__device__ __forceinline__ bf16& lds_s16(bf16* base, int row, int byteoff) {
    return *reinterpret_cast<bf16*>(
        reinterpret_cast<char*>(base) + row * 128 + (byteoff ^ ((row & 7) << 4)));
}

// async global->LDS DMA, 16B per lane; LDS dest is wave-uniform base + lane*16.
// Content swizzle via pre-swizzled per-lane GLOBAL source (rule #21).
typedef __attribute__((address_space(3))) unsigned int lds_u32;
typedef const __attribute__((address_space(1))) unsigned int glb_u32;
__device__ __forceinline__ void gload16(const void* g, void* lds) {
    __builtin_amdgcn_global_load_lds((glb_u32*)(uintptr_t)g,
                                     (lds_u32*)(unsigned int)(uintptr_t)lds,
                                     16, 0, 0);
}

// ---------------- helpers: f32 -> bf16 convert / transpose -------------------
__global__ __launch_bounds__(256) void f32_to_bf16(const float* __restrict__ in,
                                                   bf16* __restrict__ out, int n8) {
    int i = blockIdx.x * 256 + threadIdx.x;
    if (i >= n8) return;
    const float4* p = reinterpret_cast<const float4*>(in) + (size_t)i * 2;
    float4 a = p[0], b = p[1];
    bf16x8 o;
    o[0] = (bf16)a.x; o[1] = (bf16)a.y; o[2] = (bf16)a.z; o[3] = (bf16)a.w;
    o[4] = (bf16)b.x; o[5] = (bf16)b.y; o[6] = (bf16)b.z; o[7] = (bf16)b.w;
    reinterpret_cast<bf16x8*>(out)[i] = o;
}

// in[R][C] (f32) -> out[C][R] (bf16)
__global__ __launch_bounds__(256) void transpose_f32_bf16(const float* __restrict__ in,
                                                          bf16* __restrict__ out,
                                                          int R, int C) {
    int idx = blockIdx.x * 256 + threadIdx.x;
    if (idx >= R * C) return;
    int c = idx / R;
    int r = idx - c * R;
    out[idx] = (bf16)in[(size_t)r * C + c];
}

// ---------------- QKV GEMM (bf16 MFMA, dbuf DMA): [8192x768]x[768x2304] ------
__global__ __launch_bounds__(256) void gemm_qkv(const bf16* __restrict__ A,
                                                const bf16* __restrict__ Bt,
                                                const float* __restrict__ bias,
                                                bf16* __restrict__ Qo,
                                                bf16* __restrict__ Ko,
                                                bf16* __restrict__ Vto) {
    __shared__ bf16 As[2][128 * 64];
    __shared__ bf16 Bs[2][128 * 64];
    const int tid = threadIdx.x;
    const int w = tid >> 6, l = tid & 63;
    const int lane16 = l & 15, kg = l >> 4;
    const int wr = w >> 1, wc = w & 1;
    // XCD-aware bijective swizzle: 1152 blocks, each XCD gets 8 bm-rows x 18 bn
    const int flat = blockIdx.y * gridDim.x + blockIdx.x;
    const int nid = (flat & 7) * 144 + (flat >> 3);
    const int bn0 = (nid % 18) * 128, bm0 = (nid / 18) * 128;

    const int ld_r  = (w * 4) * 8 + (l >> 3);        // base row for j=0
    auto stage = [&](int k0, int buf) {
        #pragma unroll
        for (int j = 0; j < 4; ++j) {
            const int q8 = w * 4 + j;          // 1KB block 0..15
            const int r  = q8 * 8 + (l >> 3);  // tile row 0..127
            const int c16 = (l & 7) ^ (r & 7); // pre-swizzled source chunk
            gload16(A + (size_t)(bm0 + r) * Cq + k0 + c16 * 8, &As[buf][q8 * 512]);
            gload16(Bt + (size_t)(bn0 + r) * Cq + k0 + c16 * 8, &Bs[buf][q8 * 512]);
        }
    };

    f32x4 acc[4][4] = {};
    stage(0, 0);
    __syncthreads();
    for (int kt = 0; kt < 12; ++kt) {
        if (kt < 11) stage((kt + 1) * 64, (kt + 1) & 1);   // DMA overlaps compute
        bf16* Ac = As[kt & 1];
        bf16* Bc = Bs[kt & 1];
        #pragma unroll
        for (int ks = 0; ks < 2; ++ks) {
            bf16x8 af[4], bfr[4];
            #pragma unroll
            for (int m = 0; m < 4; ++m)
                af[m] = lds_v8(Ac, wr * 64 + m * 16 + lane16, ks * 64 + kg * 16);
            #pragma unroll
            for (int n = 0; n < 4; ++n)
                bfr[n] = lds_v8(Bc, wc * 64 + n * 16 + lane16, ks * 64 + kg * 16);
            #pragma unroll
            for (int m = 0; m < 4; ++m)
                #pragma unroll
                for (int n = 0; n < 4; ++n)
                    acc[m][n] = MFMA16x16x32(af[m], bfr[n], acc[m][n]);
        }
        __syncthreads();   // vmcnt drain = next buffer's DMA complete
    }
    (void)ld_r;
    const int mrow0 = bm0 + wr * 64;
    const int ncol0 = bn0 + wc * 64;
    #pragma unroll
    for (int mi = 0; mi < 4; ++mi) {
        #pragma unroll
        for (int r = 0; r < 4; ++r) {
            const int grow = mrow0 + mi * 16 + kg * 4 + r;
            const int bb = grow >> 10, tt = grow & 1023;
            #pragma unroll
            for (int ni = 0; ni < 4; ++ni) {
                const int gcol = ncol0 + ni * 16 + lane16;
                const float v = acc[mi][ni][r] + bias[gcol];
                const int which = gcol / Cq;
                const int hn = gcol - which * Cq;
                const int h = hn >> 6, d = hn & 63;
                const size_t bh = (size_t)bb * Hq + h;
                if (which == 0)      Qo[(bh * Tq + tt) * Dq + d] = (bf16)(v * 0.125f);
                else if (which == 1) Ko[(bh * Tq + tt) * Dq + d] = (bf16)v;
                else                 Vto[(bh * Dq + d) * Tq + tt] = (bf16)v;
            }
        }
    }
}

// ---------------- Flash causal attention (bf16 MFMA, paired q-tiles) ---------
// 1D grid 768; remapped so the 8 q-pair blocks of 12 heads share one XCD's L2.
__global__ __launch_bounds__(256) void attn_mfma(const bf16* __restrict__ Q,
                                                 const bf16* __restrict__ K,
                                                 const bf16* __restrict__ Vt,
                                                 bf16* __restrict__ Y) {
    __shared__ bf16 Kl[2][64 * 64];
    __shared__ bf16 Vl[2][64 * 64];
    __shared__ bf16 Pl[4 * 16 * 64];
    const int tid = threadIdx.x;
    const int w = tid >> 6, l = tid & 63;
    const int lane16 = l & 15, kg = l >> 4;
    const int id = blockIdx.x;                 // 0..767
    const int xcd = id & 7, j = id >> 3;       // j 0..95
    const int bh = xcd * 12 + (j >> 3);        // 12 heads per XCD
    const int qlo = j & 7, qhi = 15 - qlo;
    const size_t hoff = (size_t)bh * Tq * Dq;
    bf16* Pw = Pl + w * 16 * 64;
    const int qloc = w * 16 + kg * 4;

    const int qrow_lo = qlo * 64 + w * 16;
    const int qrow_hi = qhi * 64 + w * 16;
    const bf16x8 qlo0 = *reinterpret_cast<const bf16x8*>(Q + hoff + (size_t)(qrow_lo + lane16) * Dq + kg * 8);
    const bf16x8 qlo1 = *reinterpret_cast<const bf16x8*>(Q + hoff + (size_t)(qrow_lo + lane16) * Dq + 32 + kg * 8);
    const bf16x8 qhi0 = *reinterpret_cast<const bf16x8*>(Q + hoff + (size_t)(qrow_hi + lane16) * Dq + kg * 8);
    const bf16x8 qhi1 = *reinterpret_cast<const bf16x8*>(Q + hoff + (size_t)(qrow_hi + lane16) * Dq + 32 + kg * 8);

    f32x4 o_lo[4] = {}, o_hi[4] = {};
    float m_lo[4], l_lo[4], m_hi[4], l_hi[4];
    #pragma unroll
    for (int r = 0; r < 4; ++r) {
        m_lo[r] = -INFINITY; l_lo[r] = 0.f;
        m_hi[r] = -INFINITY; l_hi[r] = 0.f;
    }

    auto stage = [&](int t, int buf) {
        #pragma unroll
        for (int jj = 0; jj < 2; ++jj) {
            const int q8 = w * 2 + jj;
            const int r  = q8 * 8 + (l >> 3);
            const int c16 = (l & 7) ^ (r & 7);
            gload16(K + hoff + (size_t)(t * 64 + r) * Dq + c16 * 8, &Kl[buf][q8 * 512]);
            gload16(Vt + hoff + (size_t)r * Tq + t * 64 + c16 * 8, &Vl[buf][q8 * 512]);
        }
    };

    auto process = [&](const bf16x8& qf0, const bf16x8& qf1, f32x4* of, float* mr, float* lr,
                       bool diag, bf16* Kc, bf16* Vc) {
        f32x4 sf[4];
        #pragma unroll
        for (int f = 0; f < 4; ++f) {
            f32x4 z = {};
            z = MFMA16x16x32(qf0, lds_v8(Kc, f * 16 + lane16, kg * 16), z);
            z = MFMA16x16x32(qf1, lds_v8(Kc, f * 16 + lane16, 64 + kg * 16), z);
            sf[f] = z;
        }
        if (diag) {
            #pragma unroll
            for (int f = 0; f < 4; ++f)
                #pragma unroll
                for (int r = 0; r < 4; ++r)
                    if (f * 16 + lane16 > qloc + r) sf[f][r] = -INFINITY;
        }
        float mt[4];
        #pragma unroll
        for (int r = 0; r < 4; ++r) mt[r] = -INFINITY;
        #pragma unroll
        for (int f = 0; f < 4; ++f)
            #pragma unroll
            for (int r = 0; r < 4; ++r) mt[r] = fmaxf(mt[r], sf[f][r]);
        #pragma unroll
        for (int r = 0; r < 4; ++r) {
            #pragma unroll
            for (int m = 1; m < 16; m <<= 1) mt[r] = fmaxf(mt[r], __shfl_xor(mt[r], m));
            const float mn = fmaxf(mr[r], mt[r]);
            const float a = __expf(mr[r] - mn);
            mr[r] = mn;
            lr[r] *= a;
            #pragma unroll
            for (int dg = 0; dg < 4; ++dg) of[dg][r] *= a;
        }
        float lt[4] = {0.f, 0.f, 0.f, 0.f};
        #pragma unroll
        for (int f = 0; f < 4; ++f)
            #pragma unroll
            for (int r = 0; r < 4; ++r) {
                const float p = __expf(sf[f][r] - mr[r]);
                lt[r] += p;
                lds_s16(Pw, kg * 4 + r, (f * 16 + lane16) * 2) = (bf16)p;
            }
        #pragma unroll
        for (int r = 0; r < 4; ++r) {
            #pragma unroll
            for (int m = 1; m < 16; m <<= 1) lt[r] += __shfl_xor(lt[r], m);
            lr[r] += lt[r];
        }
        #pragma unroll
        for (int ks = 0; ks < 2; ++ks) {
            bf16x8 pf = lds_v8(Pw, lane16, ks * 64 + kg * 16);
            #pragma unroll
            for (int dg = 0; dg < 4; ++dg) {
                bf16x8 vf = lds_v8(Vc, dg * 16 + lane16, ks * 64 + kg * 16);
                of[dg] = MFMA16x16x32(pf, vf, of[dg]);
            }
        }
    };

    stage(0, 0);
    __syncthreads();

    for (int t = 0; t <= qhi; ++t) {
        if (t < qhi) stage(t + 1, (t + 1) & 1);
        bf16* Kc = Kl[t & 1];
        bf16* Vc = Vl[t & 1];
        process(qhi0, qhi1, o_hi, m_hi, l_hi, t == qhi, Kc, Vc);
        if (t <= qlo) process(qlo0, qlo1, o_lo, m_lo, l_lo, t == qlo, Kc, Vc);
        __syncthreads();
    }

    const int b = bh / Hq, h = bh - b * Hq;
    #pragma unroll
    for (int r = 0; r < 4; ++r) {
        const float ih = 1.f / l_hi[r];
        const float il = 1.f / l_lo[r];
        bf16* yh = Y + (size_t)(b * Tq + qrow_hi + kg * 4 + r) * Cq + h * Dq;
        bf16* yl = Y + (size_t)(b * Tq + qrow_lo + kg * 4 + r) * Cq + h * Dq;
        #pragma unroll
        for (int dg = 0; dg < 4; ++dg) {
            yh[dg * 16 + lane16] = (bf16)(o_hi[dg][r] * ih);
            yl[dg * 16 + lane16] = (bf16)(o_lo[dg][r] * il);
        }
    }
}

// ---------------- Proj GEMM (bf16 MFMA, dbuf DMA): [8192x768]x[768x768] ------
__global__ __launch_bounds__(256) void gemm_proj(const bf16* __restrict__ A,
                                                 const bf16* __restrict__ Bt,
                                                 const float* __restrict__ bias,
                                                 float* __restrict__ out) {
    __shared__ bf16 As[2][128 * 64];
    __shared__ bf16 Bs[2][128 * 64];
    const int tid = threadIdx.x;
    const int w = tid >> 6, l = tid & 63;
    const int lane16 = l & 15, kg = l >> 4;
    const int wr = w >> 1, wc = w & 1;
    // 384 blocks: each XCD gets 8 bm-rows x 6 bn
    const int flat = blockIdx.y * gridDim.x + blockIdx.x;
    const int nid = (flat & 7) * 48 + (flat >> 3);
    const int bn0 = (nid % 6) * 128, bm0 = (nid / 6) * 128;

    auto stage = [&](int k0, int buf) {
        #pragma unroll
        for (int j = 0; j < 4; ++j) {
            const int q8 = w * 4 + j;
            const int r  = q8 * 8 + (l >> 3);
            const int c16 = (l & 7) ^ (r & 7);
            gload16(A + (size_t)(bm0 + r) * Cq + k0 + c16 * 8, &As[buf][q8 * 512]);
            gload16(Bt + (size_t)(bn0 + r) * Cq + k0 + c16 * 8, &Bs[buf][q8 * 512]);
        }
    };

    f32x4 acc[4][4] = {};
    stage(0, 0);
    __syncthreads();
    for (int kt = 0; kt < 12; ++kt) {
        if (kt < 11) stage((kt + 1) * 64, (kt + 1) & 1);
        bf16* Ac = As[kt & 1];
        bf16* Bc = Bs[kt & 1];
        #pragma unroll
        for (int ks = 0; ks < 2; ++ks) {
            bf16x8 af[4], bfr[4];
            #pragma unroll
            for (int m = 0; m < 4; ++m)
                af[m] = lds_v8(Ac, wr * 64 + m * 16 + lane16, ks * 64 + kg * 16);
            #pragma unroll
            for (int n = 0; n < 4; ++n)
                bfr[n] = lds_v8(Bc, wc * 64 + n * 16 + lane16, ks * 64 + kg * 16);
            #pragma unroll
            for (int m = 0; m < 4; ++m)
                #pragma unroll
                for (int n = 0; n < 4; ++n)
                    acc[m][n] = MFMA16x16x32(af[m], bfr[n], acc[m][n]);
        }
        __syncthreads();
    }
    const int mrow0 = bm0 + wr * 64;
    const int ncol0 = bn0 + wc * 64;
    #pragma unroll
    for (int mi = 0; mi < 4; ++mi) {
        #pragma unroll
        for (int r = 0; r < 4; ++r) {
            const int grow = mrow0 + mi * 16 + kg * 4 + r;
            #pragma unroll
            for (int ni = 0; ni < 4; ++ni) {
                const int gcol = ncol0 + ni * 16 + lane16;
                out[(size_t)grow * Cq + gcol] = acc[mi][ni][r] + bias[gcol];
            }
        }
    }
}

extern "C" void kernel_launch(void* const* d_in, const int* in_sizes, int n_in,
                              void* d_out, int out_size, void* d_ws, size_t ws_size,
                              hipStream_t stream) {
    const float* x      = (const float*)d_in[0];
    const float* w_attn = (const float*)d_in[1];
    const float* b_attn = (const float*)d_in[2];
    const float* w_proj = (const float*)d_in[3];
    const float* b_proj = (const float*)d_in[4];
    float* out = (float*)d_out;

    char* ws = (char*)d_ws;
    bf16* Ax  = (bf16*)ws; ws += (size_t)MROWS * Cq * 2;
    bf16* WaT = (bf16*)ws; ws += (size_t)N_QKV * Cq * 2;
    bf16* WpT = (bf16*)ws; ws += (size_t)Cq * Cq * 2;
    bf16* Qw  = (bf16*)ws; ws += (size_t)MROWS * Cq * 2;   // [B,H,T,D], x0.125
    bf16* Kw  = (bf16*)ws; ws += (size_t)MROWS * Cq * 2;   // [B,H,T,D]
    bf16* Vtw = (bf16*)ws; ws += (size_t)MROWS * Cq * 2;   // [B,H,D,T]
    bf16* Yw  = (bf16*)ws; ws += (size_t)MROWS * Cq * 2;   // attn out [M][C]

    f32_to_bf16<<<(MROWS * Cq / 8 + 255) / 256, 256, 0, stream>>>(x, Ax, MROWS * Cq / 8);
    transpose_f32_bf16<<<(Cq * N_QKV + 255) / 256, 256, 0, stream>>>(w_attn, WaT, Cq, N_QKV);
    transpose_f32_bf16<<<(Cq * Cq + 255) / 256, 256, 0, stream>>>(w_proj, WpT, Cq, Cq);
    gemm_qkv<<<dim3(18, 64), 256, 0, stream>>>(Ax, WaT, b_attn, Qw, Kw, Vtw);
    attn_mfma<<<dim3(768), 256, 0, stream>>>(Qw, Kw, Vtw, Yw);
    gemm_proj<<<dim3(6, 64), 256, 0, stream>>>(Yw, WpT, b_proj, out);
}